// Round 4
// baseline (209.853 us; speedup 1.0000x reference)
//
#include <hip/hip_runtime.h>
#include <math.h>

// Attention1D: B=4, L=4096, C=F=64, fp32 in/out.
// scores = (Q K^T)/8 ; softmax over QUERY axis (per-k column sums);
// out = P @ V + x = E @ (diag(rl) V') + x, E = exp(S/8).
// k_stats folds rl into V^T; k_out recomputes E and does PV with the
// P-fragment built IN REGISTERS via ds_bpermute lane permutation (no LDS).

#define BB 4
#define LL 4096
#define CC 64

typedef __attribute__((ext_vector_type(8))) short bf16x8;
typedef __attribute__((ext_vector_type(4))) float f32x4;

#define MFMA(a, b, cacc) __builtin_amdgcn_mfma_f32_16x16x32_bf16(a, b, cacc, 0, 0, 0)

static __device__ __forceinline__ unsigned short f2bf(float f) {
    union { float f; unsigned u; } v; v.f = f;
    unsigned r = v.u + 0x7FFFu + ((v.u >> 16) & 1u);
    return (unsigned short)(r >> 16);
}
static __device__ __forceinline__ float bf2f(unsigned short h) {
    union { unsigned u; float f; } v; v.u = ((unsigned)h) << 16; return v.f;
}
static __device__ __forceinline__ bf16x8 pack8(float4 a, float4 b) {
    bf16x8 r;
    r[0] = (short)f2bf(a.x); r[1] = (short)f2bf(a.y);
    r[2] = (short)f2bf(a.z); r[3] = (short)f2bf(a.w);
    r[4] = (short)f2bf(b.x); r[5] = (short)f2bf(b.y);
    r[6] = (short)f2bf(b.z); r[7] = (short)f2bf(b.w);
    return r;
}
static __device__ __forceinline__ unsigned cvtpk(float lo, float hi) {
    unsigned r;
    asm("v_cvt_pk_bf16_f32 %0, %1, %2" : "=v"(r) : "v"(lo), "v"(hi));
    return r;
}
static __device__ __forceinline__ bf16x8 frag_from_dw(unsigned d0, unsigned d1,
                                                      unsigned d2, unsigned d3) {
    union { unsigned u[4]; bf16x8 f; } t;
    t.u[0] = d0; t.u[1] = d1; t.u[2] = d2; t.u[3] = d3;
    return t.f;
}

// ---------------- K1: projections via MFMA -> bf16 Q, K, V^T ----------------
__global__ __launch_bounds__(512) void k_qkv(
    const float* __restrict__ x,
    const float* __restrict__ Wq, const float* __restrict__ bq,
    const float* __restrict__ Wk, const float* __restrict__ bk,
    const float* __restrict__ Wv, const float* __restrict__ bv,
    unsigned short* __restrict__ Qb, unsigned short* __restrict__ Kb,
    unsigned short* __restrict__ Vt)
{
    __shared__ unsigned short ldsV[64 * 72];
    const int bid = blockIdx.x;
    const int mat = bid % 3;          // 0:Q 1:K 2:V
    const int r0 = (bid / 3) * 64;
    const int tid = threadIdx.x, w = tid >> 6, lane = tid & 63;
    const int c = lane & 15, g = lane >> 4;
    const int rw = (w >> 1) * 16;
    const int c0 = (w & 1) * 32;

    const float* W  = (mat == 0) ? Wq : (mat == 1) ? Wk : Wv;
    const float* bs = (mat == 0) ? bq : (mat == 1) ? bk : bv;

    const float* xr = x + (size_t)(r0 + rw + c) * CC;
    const bf16x8 ax0 = pack8(((const float4*)xr)[2 * g], ((const float4*)xr)[2 * g + 1]);
    const bf16x8 ax1 = pack8(((const float4*)xr)[8 + 2 * g], ((const float4*)xr)[8 + 2 * g + 1]);

    f32x4 acc0 = {0.f, 0.f, 0.f, 0.f}, acc1 = {0.f, 0.f, 0.f, 0.f};
    {
        const int col = c0 + c;
        bf16x8 b0, b1;
        #pragma unroll
        for (int j = 0; j < 8; ++j) {
            b0[j] = (short)f2bf(W[(8 * g + j) * 64 + col]);
            b1[j] = (short)f2bf(W[(32 + 8 * g + j) * 64 + col]);
        }
        acc0 = MFMA(ax0, b0, acc0); acc0 = MFMA(ax1, b1, acc0);
    }
    {
        const int col = c0 + 16 + c;
        bf16x8 b0, b1;
        #pragma unroll
        for (int j = 0; j < 8; ++j) {
            b0[j] = (short)f2bf(W[(8 * g + j) * 64 + col]);
            b1[j] = (short)f2bf(W[(32 + 8 * g + j) * 64 + col]);
        }
        acc1 = MFMA(ax0, b0, acc1); acc1 = MFMA(ax1, b1, acc1);
    }
    const float bias0 = bs[c0 + c], bias1 = bs[c0 + 16 + c];

    if (mat < 2) {
        unsigned short* dst = (mat == 0) ? Qb : Kb;
        #pragma unroll
        for (int r = 0; r < 4; ++r) {
            const size_t row = (size_t)(r0 + rw + 4 * g + r) * CC;
            dst[row + c0 + c]      = f2bf(acc0[r] + bias0);
            dst[row + c0 + 16 + c] = f2bf(acc1[r] + bias1);
        }
    } else {
        #pragma unroll
        for (int r = 0; r < 4; ++r) {
            const int rowin = rw + 4 * g + r;
            ldsV[(c0 + c) * 72 + rowin]      = f2bf(acc0[r] + bias0);
            ldsV[(c0 + 16 + c) * 72 + rowin] = f2bf(acc1[r] + bias1);
        }
        __syncthreads();
        const int b = r0 >> 12, rin = r0 & 4095;
        const int f = tid >> 3, jj = tid & 7;
        *(uint4*)(Vt + ((size_t)(b * 64 + f)) * LL + rin + jj * 8) =
            *(const uint4*)(ldsV + f * 72 + jj * 8);
    }
}

// ---------------- K2: column sums -> rescale V^T in place ----------------
// grid = B*(L/32) x 512 (8 waves = 2 k-subtiles x 4 q-quarters).
// Manual 2-set register pipeline, sched_barrier-fenced.
__global__ __launch_bounds__(512, 4) void k_stats(
    const unsigned short* __restrict__ Qb, const unsigned short* __restrict__ Kb,
    unsigned short* __restrict__ Vt)
{
    const int nb = ((blockIdx.x & 7) << 6) | (blockIdx.x >> 3);  // XCD swizzle (512%8==0)
    const int b = nb >> 7, kt = nb & 127;
    const int kbase = kt * 32;
    const int tid = threadIdx.x, w = tid >> 6, lane = tid & 63;
    const int c = lane & 15, g = lane >> 4;
    const int ksub = w & 1, qq = w >> 1;

    const size_t krow = ((size_t)b * LL + kbase + ksub * 16 + c) * CC;
    const bf16x8 bk0 = *(const bf16x8*)(Kb + krow + 8 * g);
    const bf16x8 bk1 = *(const bf16x8*)(Kb + krow + 32 + 8 * g);

    const unsigned short* const qp = Qb + ((size_t)b * LL + qq * 1024 + c) * CC + 8 * g;
    float l0 = 0.f, l1 = 0.f, l2 = 0.f, l3 = 0.f;

    bf16x8 aA0, aA1, aB0, aB1;
    #define SLOADA(S, idx) do { \
        const size_t qo = (size_t)(idx) * 16 * CC; \
        S##0 = *(const bf16x8*)(qp + qo); \
        S##1 = *(const bf16x8*)(qp + qo + 32); \
    } while (0)
    #define SSTEP(A0, A1) do { \
        f32x4 T = {0.f, 0.f, 0.f, 0.f}; \
        T = MFMA(A0, bk0, T); T = MFMA(A1, bk1, T); \
        l0 += __expf(T[0] * 0.125f); l1 += __expf(T[1] * 0.125f); \
        l2 += __expf(T[2] * 0.125f); l3 += __expf(T[3] * 0.125f); \
    } while (0)

    SLOADA(aA, 0);
    for (int s = 0; s < 64; s += 2) {
        SLOADA(aB, s + 1);
        __builtin_amdgcn_sched_barrier(0);
        SSTEP(aA0, aA1);
        SLOADA(aA, (s + 2) & 63);
        __builtin_amdgcn_sched_barrier(0);
        SSTEP(aB0, aB1);
    }
    float ls = (l0 + l1) + (l2 + l3);
    ls += __shfl_xor(ls, 16);
    ls += __shfl_xor(ls, 32);

    __shared__ float pl[8][16];
    __shared__ float rls[32];
    if (lane < 16) pl[w][c] = ls;
    __syncthreads();
    if (tid < 32) {
        const int ks2 = tid >> 4, c2 = tid & 15;
        const float L = (pl[ks2][c2] + pl[2 + ks2][c2]) + (pl[4 + ks2][c2] + pl[6 + ks2][c2]);
        rls[tid] = 1.0f / L;
    }
    __syncthreads();

    const int f = tid >> 3, jj = tid & 7;
    unsigned short* vp = Vt + ((size_t)(b * 64 + f)) * LL + kbase + jj * 4;
    ushort4 v = *(const ushort4*)vp;
    v.x = f2bf(bf2f(v.x) * rls[jj * 4 + 0]);
    v.y = f2bf(bf2f(v.y) * rls[jj * 4 + 1]);
    v.z = f2bf(bf2f(v.z) * rls[jj * 4 + 2]);
    v.w = f2bf(bf2f(v.w) * rls[jj * 4 + 3]);
    *(ushort4*)vp = v;
}

// ---------------- K3: out = E @ V' + x ----------------
// grid = B*(L/32) x 512 (8 waves = 2 q-subtiles x 4 k-splits).
// S^T via mfma(K,Q); P-fragment for PV built in registers:
// lane(c,g) has k=4g..4g+3 (+16), needs k=8g..8g+7 -> 8 ds_bpermute + 4 selects.
// Manual 2-set register pipeline, sched_barrier-fenced. No in-loop LDS/barriers.
__global__ __launch_bounds__(512, 4) void k_out(
    const float* __restrict__ x,
    const unsigned short* __restrict__ Qb, const unsigned short* __restrict__ Kb,
    const unsigned short* __restrict__ Vt,
    float* __restrict__ out)
{
    const int nb = ((blockIdx.x & 7) << 6) | (blockIdx.x >> 3);  // XCD swizzle
    const int b = nb >> 7, qt = nb & 127;
    const int tid = threadIdx.x, w = tid >> 6, lane = tid & 63;
    const int c = lane & 15, g = lane >> 4;
    const int qsub = w & 1, ksp = w >> 1;
    const int q0 = qt * 32 + qsub * 16;

    __shared__ float ocomb[32][64];

    // shuffle source lanes (loop-invariant): row c, source g' = 2*(g&1) (+1)
    const int sl_lo = c + 32 * (g & 1);
    const int sl_hi = sl_lo + 16;
    const bool hi32 = (g >= 2);

    // Q B-frags (loop-invariant)
    const size_t qrow = ((size_t)b * LL + q0 + c) * CC;
    const bf16x8 bq0 = *(const bf16x8*)(Qb + qrow + 8 * g);
    const bf16x8 bq1 = *(const bf16x8*)(Qb + qrow + 32 + 8 * g);

    const unsigned short* const kbp = Kb + ((size_t)b * LL + c) * CC + 8 * g;
    const unsigned short* const vbp = Vt + ((size_t)(b * 64) + c) * LL + 8 * g;
    const int kbeg = ksp * 1024;

    f32x4 oacc[4];
    #pragma unroll
    for (int i = 0; i < 4; ++i) oacc[i] = (f32x4){0.f, 0.f, 0.f, 0.f};

    bf16x8 kA0, kA1, kA2, kA3, vA0, vA1, vA2, vA3;
    bf16x8 kB0, kB1, kB2, kB3, vB0, vB1, vB2, vB3;

    #define LOADK(S, idx) do { \
        const size_t ko = (size_t)(kbeg + (idx) * 32) * CC; \
        S##0 = *(const bf16x8*)(kbp + ko); \
        S##1 = *(const bf16x8*)(kbp + ko + 32); \
        S##2 = *(const bf16x8*)(kbp + ko + 16 * CC); \
        S##3 = *(const bf16x8*)(kbp + ko + 16 * CC + 32); \
    } while (0)
    #define LOADV(S, idx) do { \
        const size_t vo = (size_t)(kbeg + (idx) * 32); \
        S##0 = *(const bf16x8*)(vbp + vo); \
        S##1 = *(const bf16x8*)(vbp + 16 * LL + vo); \
        S##2 = *(const bf16x8*)(vbp + 32 * LL + vo); \
        S##3 = *(const bf16x8*)(vbp + 48 * LL + vo); \
    } while (0)
    #define STEP(K0, K1, K2, K3, V0, V1, V2, V3) do { \
        f32x4 T0 = {0.f, 0.f, 0.f, 0.f}, T1 = {0.f, 0.f, 0.f, 0.f}; \
        T0 = MFMA(K0, bq0, T0); T0 = MFMA(K1, bq1, T0); \
        T1 = MFMA(K2, bq0, T1); T1 = MFMA(K3, bq1, T1); \
        const unsigned w0 = cvtpk(__expf(T0[0] * 0.125f), __expf(T0[1] * 0.125f)); \
        const unsigned w1 = cvtpk(__expf(T0[2] * 0.125f), __expf(T0[3] * 0.125f)); \
        const unsigned w2 = cvtpk(__expf(T1[0] * 0.125f), __expf(T1[1] * 0.125f)); \
        const unsigned w3 = cvtpk(__expf(T1[2] * 0.125f), __expf(T1[3] * 0.125f)); \
        const unsigned a0 = (unsigned)__shfl((int)w0, sl_lo); \
        const unsigned a1 = (unsigned)__shfl((int)w1, sl_lo); \
        const unsigned a2 = (unsigned)__shfl((int)w0, sl_hi); \
        const unsigned a3 = (unsigned)__shfl((int)w1, sl_hi); \
        const unsigned b0 = (unsigned)__shfl((int)w2, sl_lo); \
        const unsigned b1 = (unsigned)__shfl((int)w3, sl_lo); \
        const unsigned b2 = (unsigned)__shfl((int)w2, sl_hi); \
        const unsigned b3 = (unsigned)__shfl((int)w3, sl_hi); \
        const bf16x8 pa = frag_from_dw(hi32 ? b0 : a0, hi32 ? b1 : a1, \
                                       hi32 ? b2 : a2, hi32 ? b3 : a3); \
        oacc[0] = MFMA(pa, V0, oacc[0]); \
        oacc[1] = MFMA(pa, V1, oacc[1]); \
        oacc[2] = MFMA(pa, V2, oacc[2]); \
        oacc[3] = MFMA(pa, V3, oacc[3]); \
    } while (0)

    LOADK(kA, 0); LOADV(vA, 0);
    for (int s = 0; s < 32; s += 2) {
        LOADK(kB, s + 1); LOADV(vB, s + 1);
        __builtin_amdgcn_sched_barrier(0);
        STEP(kA0, kA1, kA2, kA3, vA0, vA1, vA2, vA3);
        LOADK(kA, (s + 2) & 31); LOADV(vA, (s + 2) & 31);
        __builtin_amdgcn_sched_barrier(0);
        STEP(kB0, kB1, kB2, kB3, vB0, vB1, vB2, vB3);
    }

    // combine the 4 k-split partials
    for (int i = tid; i < 32 * 64; i += 512) ((float*)ocomb)[i] = 0.f;
    __syncthreads();
    #pragma unroll
    for (int ft = 0; ft < 4; ++ft) {
        #pragma unroll
        for (int r = 0; r < 4; ++r)
            atomicAdd(&ocomb[qsub * 16 + 4 * g + r][ft * 16 + c], oacc[ft][r]);
    }
    __syncthreads();
    {
        const int q = tid >> 4, fc = tid & 15;
        const size_t row = (size_t)b * LL + qt * 32 + q;
        const float4 xv = ((const float4*)(x + row * CC))[fc];
        const float4 ov = ((const float4*)&ocomb[q][0])[fc];
        ((float4*)(out + row * CC))[fc] =
            make_float4(xv.x + ov.x, xv.y + ov.y, xv.z + ov.z, xv.w + ov.w);
    }
}

extern "C" void kernel_launch(void* const* d_in, const int* in_sizes, int n_in,
                              void* d_out, int out_size, void* d_ws, size_t ws_size,
                              hipStream_t stream)
{
    const float* x  = (const float*)d_in[0];
    const float* Wq = (const float*)d_in[1];
    const float* bq = (const float*)d_in[2];
    const float* Wk = (const float*)d_in[3];
    const float* bk = (const float*)d_in[4];
    const float* Wv = (const float*)d_in[5];
    const float* bv = (const float*)d_in[6];
    float* out = (float*)d_out;

    const size_t n = (size_t)BB * LL * CC;
    unsigned short* Qb = (unsigned short*)d_ws;
    unsigned short* Kb = Qb + n;
    unsigned short* Vt = Kb + n;

    hipLaunchKernelGGL(k_qkv, dim3(3 * BB * LL / 64), dim3(512), 0, stream,
                       x, Wq, bq, Wk, bk, Wv, bv, Qb, Kb, Vt);
    hipLaunchKernelGGL(k_stats, dim3(BB * (LL / 32)), dim3(512), 0, stream,
                       Qb, Kb, Vt);
    hipLaunchKernelGGL(k_out, dim3(BB * (LL / 32)), dim3(512), 0, stream,
                       x, Qb, Kb, Vt, out);
}

// Round 6
// 130.963 us; speedup vs baseline: 1.6024x; 1.6024x over previous
//
#include <hip/hip_runtime.h>
#include <math.h>

// Attention1D: B=4, L=4096, C=F=64, fp32 in/out.
// scores=(QK^T)/8; softmax over QUERY axis; out = P@V + x = E@(diag(rl)V) + x.
// k_stats folds rl into V^T. All matmuls mfma_f32_32x32x16_bf16 with
// swapped-operand S^T so PV fragments assemble in-register (shfl_xor(32)).
// Loads: inline-asm global_load_dwordx4 + counted s_waitcnt vmcnt(N)
// (compiler-proof software pipeline, depth 2, split K/V waits).

#define BB 4
#define LL 4096
#define CC 64
#define C2 0.18033688011112042f  // 0.125 * log2(e)

typedef __attribute__((ext_vector_type(8)))  short bf16x8;
typedef __attribute__((ext_vector_type(4)))  float f32x4;
typedef __attribute__((ext_vector_type(16))) float f32x16;
typedef __attribute__((ext_vector_type(4)))  unsigned int u32x4;

#define MFMA16(a, b, c) __builtin_amdgcn_mfma_f32_16x16x32_bf16(a, b, c, 0, 0, 0)
#define MFMA32(a, b, c) __builtin_amdgcn_mfma_f32_32x32x16_bf16(a, b, c, 0, 0, 0)
#define EXP2(x) __builtin_amdgcn_exp2f(x)

#define GLD4(dst, voff, base, imm) \
    asm volatile("global_load_dwordx4 %0, %1, %2 offset:%c3" \
                 : "=v"(dst) : "v"(voff), "s"(base), "i"(imm))
#define WAITVM(n) asm volatile("s_waitcnt vmcnt(" #n ")")
#define SBAR() __builtin_amdgcn_sched_barrier(0)

static __device__ __forceinline__ bf16x8 asbf(u32x4 v) {
    union { u32x4 a; bf16x8 b; } u; u.a = v; return u.b;
}
static __device__ __forceinline__ unsigned short f2bf(float f) {
    union { float f; unsigned u; } v; v.f = f;
    unsigned r = v.u + 0x7FFFu + ((v.u >> 16) & 1u);
    return (unsigned short)(r >> 16);
}
static __device__ __forceinline__ float bf2f(unsigned short h) {
    union { unsigned u; float f; } v; v.u = ((unsigned)h) << 16; return v.f;
}
static __device__ __forceinline__ bf16x8 pack8(float4 a, float4 b) {
    bf16x8 r;
    r[0] = (short)f2bf(a.x); r[1] = (short)f2bf(a.y);
    r[2] = (short)f2bf(a.z); r[3] = (short)f2bf(a.w);
    r[4] = (short)f2bf(b.x); r[5] = (short)f2bf(b.y);
    r[6] = (short)f2bf(b.z); r[7] = (short)f2bf(b.w);
    return r;
}
static __device__ __forceinline__ unsigned cvtpk(float lo, float hi) {
    unsigned r;
    asm("v_cvt_pk_bf16_f32 %0, %1, %2" : "=v"(r) : "v"(lo), "v"(hi));
    return r;
}

// ---------------- K1: projections via MFMA -> bf16 Q, K, V^T ----------------
__global__ __launch_bounds__(512) void k_qkv(
    const float* __restrict__ x,
    const float* __restrict__ Wq, const float* __restrict__ bq,
    const float* __restrict__ Wk, const float* __restrict__ bk,
    const float* __restrict__ Wv, const float* __restrict__ bv,
    unsigned short* __restrict__ Qb, unsigned short* __restrict__ Kb,
    unsigned short* __restrict__ Vt)
{
    __shared__ unsigned short ldsV[64 * 72];
    const int bid = blockIdx.x;
    const int mat = bid % 3;          // 0:Q 1:K 2:V
    const int r0 = (bid / 3) * 64;
    const int tid = threadIdx.x, w = tid >> 6, lane = tid & 63;
    const int c = lane & 15, g = lane >> 4;
    const int rw = (w >> 1) * 16;
    const int c0 = (w & 1) * 32;

    const float* W  = (mat == 0) ? Wq : (mat == 1) ? Wk : Wv;
    const float* bs = (mat == 0) ? bq : (mat == 1) ? bk : bv;

    const float* xr = x + (size_t)(r0 + rw + c) * CC;
    const bf16x8 ax0 = pack8(((const float4*)xr)[2 * g], ((const float4*)xr)[2 * g + 1]);
    const bf16x8 ax1 = pack8(((const float4*)xr)[8 + 2 * g], ((const float4*)xr)[8 + 2 * g + 1]);

    f32x4 acc0 = {0.f, 0.f, 0.f, 0.f}, acc1 = {0.f, 0.f, 0.f, 0.f};
    {
        const int col = c0 + c;
        bf16x8 b0, b1;
        #pragma unroll
        for (int j = 0; j < 8; ++j) {
            b0[j] = (short)f2bf(W[(8 * g + j) * 64 + col]);
            b1[j] = (short)f2bf(W[(32 + 8 * g + j) * 64 + col]);
        }
        acc0 = MFMA16(ax0, b0, acc0); acc0 = MFMA16(ax1, b1, acc0);
    }
    {
        const int col = c0 + 16 + c;
        bf16x8 b0, b1;
        #pragma unroll
        for (int j = 0; j < 8; ++j) {
            b0[j] = (short)f2bf(W[(8 * g + j) * 64 + col]);
            b1[j] = (short)f2bf(W[(32 + 8 * g + j) * 64 + col]);
        }
        acc1 = MFMA16(ax0, b0, acc1); acc1 = MFMA16(ax1, b1, acc1);
    }
    const float bias0 = bs[c0 + c], bias1 = bs[c0 + 16 + c];

    if (mat < 2) {
        unsigned short* dst = (mat == 0) ? Qb : Kb;
        #pragma unroll
        for (int r = 0; r < 4; ++r) {
            const size_t row = (size_t)(r0 + rw + 4 * g + r) * CC;
            dst[row + c0 + c]      = f2bf(acc0[r] + bias0);
            dst[row + c0 + 16 + c] = f2bf(acc1[r] + bias1);
        }
    } else {
        #pragma unroll
        for (int r = 0; r < 4; ++r) {
            const int rowin = rw + 4 * g + r;
            ldsV[(c0 + c) * 72 + rowin]      = f2bf(acc0[r] + bias0);
            ldsV[(c0 + 16 + c) * 72 + rowin] = f2bf(acc1[r] + bias1);
        }
        __syncthreads();
        const int b = r0 >> 12, rin = r0 & 4095;
        const int f = tid >> 3, jj = tid & 7;
        *(uint4*)(Vt + ((size_t)(b * 64 + f)) * LL + rin + jj * 8) =
            *(const uint4*)(ldsV + f * 72 + jj * 8);
    }
}

// ---------------- K2: column sums -> rescale V^T in place ----------------
// grid = B*(L/32) x 256 (4 waves x 1024 q = 32 steps of 32q).
// S^T tile 32k x 32q = mfma32(A=K rows [reg-resident], B=Q [asm-pipelined]).
__global__ __launch_bounds__(256, 4) void k_stats(
    const unsigned short* __restrict__ Qb, const unsigned short* __restrict__ Kb,
    unsigned short* __restrict__ Vt)
{
    const int nb = ((blockIdx.x & 7) << 6) | (blockIdx.x >> 3);  // XCD swizzle
    const int b = nb >> 7, kt = nb & 127;
    const int kbase = kt * 32;
    const int tid = threadIdx.x, w = tid >> 6, lane = tid & 63;
    const int l31 = lane & 31, hi = lane >> 5;

    __shared__ float pl[4][32];
    __shared__ float rls[32];

    // A-frags (loop-invariant): K row kbase+l31, c = c0 + 8*hi + j
    const unsigned short* kr = Kb + ((size_t)b * LL + kbase + l31) * CC + 8 * hi;
    const bf16x8 ak0 = *(const bf16x8*)(kr);
    const bf16x8 ak1 = *(const bf16x8*)(kr + 16);
    const bf16x8 ak2 = *(const bf16x8*)(kr + 32);
    const bf16x8 ak3 = *(const bf16x8*)(kr + 48);

    const unsigned short* const sQ = Qb + (size_t)b * LL * CC;
    unsigned voffQ = (unsigned)(((w * 1024 + l31) * CC + 8 * hi) * 2);

    u32x4 qA0, qA1, qA2, qA3, qB0, qB1, qB2, qB3;
    #define QISSUE(P) do { \
        GLD4(P##0, voffQ, sQ, 0);  GLD4(P##1, voffQ, sQ, 32); \
        GLD4(P##2, voffQ, sQ, 64); GLD4(P##3, voffQ, sQ, 96); \
        voffQ += 32 * CC * 2; \
    } while (0)

    QISSUE(qA); QISSUE(qB);

    f32x16 lacc = {};
    #define QHALF(P) do { \
        WAITVM(4); SBAR(); \
        f32x16 T = {}; \
        T = MFMA32(ak0, asbf(P##0), T); \
        T = MFMA32(ak1, asbf(P##1), T); \
        T = MFMA32(ak2, asbf(P##2), T); \
        T = MFMA32(ak3, asbf(P##3), T); \
        QISSUE(P); \
        _Pragma("unroll") \
        for (int r = 0; r < 16; ++r) lacc[r] += EXP2(T[r] * C2); \
    } while (0)

    for (int s = 0; s < 32; s += 2) {   // overreads 2 steps at end: inside ws, unused
        QHALF(qA);
        QHALF(qB);
    }
    asm volatile("s_waitcnt vmcnt(0)");
    #undef QHALF
    #undef QISSUE

    // reduce each reg across the 32 lanes of each half (sum over q)
    #pragma unroll
    for (int r = 0; r < 16; ++r) {
        float v = lacc[r];
        v += __shfl_xor(v, 1);  v += __shfl_xor(v, 2);
        v += __shfl_xor(v, 4);  v += __shfl_xor(v, 8);
        v += __shfl_xor(v, 16);
        lacc[r] = v;
    }
    if (l31 == 0) {
        #pragma unroll
        for (int r = 0; r < 16; ++r)
            pl[w][(r & 3) + 8 * (r >> 2) + 4 * hi] = lacc[r];
    }
    __syncthreads();
    if (tid < 32) {
        const float L = (pl[0][tid] + pl[1][tid]) + (pl[2][tid] + pl[3][tid]);
        rls[tid] = 1.0f / L;
    }
    __syncthreads();

    // rescale V^T in place: 64 f rows x 32 k, 8 k per thread
    {
        const int f = tid >> 2, jj = tid & 3;
        unsigned short* vp = Vt + ((size_t)(b * 64 + f)) * LL + kbase + jj * 8;
        ushort4 v0 = ((const ushort4*)vp)[0], v1 = ((const ushort4*)vp)[1];
        v0.x = f2bf(bf2f(v0.x) * rls[jj * 8 + 0]);
        v0.y = f2bf(bf2f(v0.y) * rls[jj * 8 + 1]);
        v0.z = f2bf(bf2f(v0.z) * rls[jj * 8 + 2]);
        v0.w = f2bf(bf2f(v0.w) * rls[jj * 8 + 3]);
        v1.x = f2bf(bf2f(v1.x) * rls[jj * 8 + 4]);
        v1.y = f2bf(bf2f(v1.y) * rls[jj * 8 + 5]);
        v1.z = f2bf(bf2f(v1.z) * rls[jj * 8 + 6]);
        v1.w = f2bf(bf2f(v1.w) * rls[jj * 8 + 7]);
        ((ushort4*)vp)[0] = v0; ((ushort4*)vp)[1] = v1;
    }
}

// ---------------- K3: out = E @ V' + x ----------------
// grid = B*(L/32) x 256 (4 waves x 1024 k = 32 steps of 32k).
// Per step: S^T tile (4 mfma) -> exp -> cvt_pk -> shfl_xor(32) assembles
// PV fragments in-register -> O^T += V'A x P (4 mfma). Asm pipeline depth 2,
// split waits vmcnt(12): K arrives for S while V still flies for PV.
__global__ __launch_bounds__(256, 3) void k_out(
    const float* __restrict__ x,
    const unsigned short* __restrict__ Qb, const unsigned short* __restrict__ Kb,
    const unsigned short* __restrict__ Vt,
    float* __restrict__ out)
{
    const int nb = ((blockIdx.x & 7) << 6) | (blockIdx.x >> 3);  // XCD swizzle
    const int b = nb >> 7, qt = nb & 127;
    const int q0 = qt * 32;
    const int tid = threadIdx.x, w = tid >> 6, lane = tid & 63;
    const int l31 = lane & 31, hi = lane >> 5;

    __shared__ float ocomb[32][68];   // pad 68: 4-way banks on atomics, 16B-aligned rows

    // Q B-frags (loop-invariant): col=q0+l31, c = c0 + 8*hi + j
    const unsigned short* qr = Qb + ((size_t)b * LL + q0 + l31) * CC + 8 * hi;
    const bf16x8 qb0 = *(const bf16x8*)(qr);
    const bf16x8 qb1 = *(const bf16x8*)(qr + 16);
    const bf16x8 qb2 = *(const bf16x8*)(qr + 32);
    const bf16x8 qb3 = *(const bf16x8*)(qr + 48);

    const unsigned short* const sK = Kb + (size_t)b * LL * CC;
    const unsigned short* const sV = Vt + (size_t)b * 64 * LL;
    unsigned voffK  = (unsigned)(((w * 1024 + l31) * CC + 8 * hi) * 2);
    unsigned voffV0 = (unsigned)(((size_t)l31 * LL + w * 1024 + 8 * hi) * 2);
    unsigned voffV1 = voffV0 + 32 * LL * 2;

    u32x4 Ak0, Ak1, Ak2, Ak3, Av0, Av1, Av2, Av3;
    u32x4 Bk0, Bk1, Bk2, Bk3, Bv0, Bv1, Bv2, Bv3;

    #define KISSUE(P) do { \
        GLD4(P##k0, voffK, sK, 0);  GLD4(P##k1, voffK, sK, 32); \
        GLD4(P##k2, voffK, sK, 64); GLD4(P##k3, voffK, sK, 96); \
        voffK += 32 * CC * 2; \
    } while (0)
    #define VISSUE(P) do { \
        GLD4(P##v0, voffV0, sV, 0); GLD4(P##v1, voffV0, sV, 32); \
        GLD4(P##v2, voffV1, sV, 0); GLD4(P##v3, voffV1, sV, 32); \
        voffV0 += 64; voffV1 += 64; \
    } while (0)

    KISSUE(A); VISSUE(A);
    KISSUE(B); VISSUE(B);

    f32x16 oacc0 = {}, oacc1 = {};

    #define OHALF(P) do { \
        WAITVM(12); SBAR(); \
        f32x16 T = {}; \
        T = MFMA32(asbf(P##k0), qb0, T); \
        T = MFMA32(asbf(P##k1), qb1, T); \
        T = MFMA32(asbf(P##k2), qb2, T); \
        T = MFMA32(asbf(P##k3), qb3, T); \
        KISSUE(P); \
        const unsigned u0 = cvtpk(EXP2(T[0] * C2),  EXP2(T[1] * C2)); \
        const unsigned u1 = cvtpk(EXP2(T[2] * C2),  EXP2(T[3] * C2)); \
        const unsigned u2 = cvtpk(EXP2(T[4] * C2),  EXP2(T[5] * C2)); \
        const unsigned u3 = cvtpk(EXP2(T[6] * C2),  EXP2(T[7] * C2)); \
        const unsigned u4 = cvtpk(EXP2(T[8] * C2),  EXP2(T[9] * C2)); \
        const unsigned u5 = cvtpk(EXP2(T[10] * C2), EXP2(T[11] * C2)); \
        const unsigned u6 = cvtpk(EXP2(T[12] * C2), EXP2(T[13] * C2)); \
        const unsigned u7 = cvtpk(EXP2(T[14] * C2), EXP2(T[15] * C2)); \
        const unsigned t0 = (unsigned)__shfl_xor((int)u0, 32); \
        const unsigned t1 = (unsigned)__shfl_xor((int)u1, 32); \
        const unsigned t2 = (unsigned)__shfl_xor((int)u2, 32); \
        const unsigned t3 = (unsigned)__shfl_xor((int)u3, 32); \
        const unsigned t4 = (unsigned)__shfl_xor((int)u4, 32); \
        const unsigned t5 = (unsigned)__shfl_xor((int)u5, 32); \
        const unsigned t6 = (unsigned)__shfl_xor((int)u6, 32); \
        const unsigned t7 = (unsigned)__shfl_xor((int)u7, 32); \
        u32x4 f1, f2; \
        f1[0] = hi ? t2 : u0;  f1[1] = hi ? t3 : u1; \
        f1[2] = hi ? u2 : t0;  f1[3] = hi ? u3 : t1; \
        f2[0] = hi ? t6 : u4;  f2[1] = hi ? t7 : u5; \
        f2[2] = hi ? u6 : t4;  f2[3] = hi ? u7 : t5; \
        WAITVM(12); SBAR(); \
        oacc0 = MFMA32(asbf(P##v0), asbf(f1), oacc0); \
        oacc0 = MFMA32(asbf(P##v1), asbf(f2), oacc0); \
        oacc1 = MFMA32(asbf(P##v2), asbf(f1), oacc1); \
        oacc1 = MFMA32(asbf(P##v3), asbf(f2), oacc1); \
        VISSUE(P); \
    } while (0)

    for (int s = 0; s < 32; s += 2) {   // final reissues overread ~2 steps: inside ws
        OHALF(A);
        OHALF(B);
    }
    asm volatile("s_waitcnt vmcnt(0)");
    #undef OHALF
    #undef KISSUE
    #undef VISSUE

    // combine 4 waves' partial O^T tiles (col=q=l31, row f'=(r&3)+8*(r>>2)+4*hi)
    for (int i = tid; i < 32 * 68; i += 256) ((float*)ocomb)[i] = 0.f;
    __syncthreads();
    #pragma unroll
    for (int r = 0; r < 16; ++r) {
        const int fr = (r & 3) + 8 * (r >> 2) + 4 * hi;
        atomicAdd(&ocomb[l31][fr],      oacc0[r]);
        atomicAdd(&ocomb[l31][32 + fr], oacc1[r]);
    }
    __syncthreads();
    {
        const int q = tid >> 3, f8 = (tid & 7) * 8;
        const size_t row = (size_t)b * LL + q0 + q;
        const float4 xv0 = ((const float4*)(x + row * CC))[(f8 >> 2)];
        const float4 xv1 = ((const float4*)(x + row * CC))[(f8 >> 2) + 1];
        const float4 ov0 = *(const float4*)(&ocomb[q][f8]);
        const float4 ov1 = *(const float4*)(&ocomb[q][f8 + 4]);
        ((float4*)(out + row * CC))[(f8 >> 2)]     =
            make_float4(xv0.x + ov0.x, xv0.y + ov0.y, xv0.z + ov0.z, xv0.w + ov0.w);
        ((float4*)(out + row * CC))[(f8 >> 2) + 1] =
            make_float4(xv1.x + ov1.x, xv1.y + ov1.y, xv1.z + ov1.z, xv1.w + ov1.w);
    }
}

extern "C" void kernel_launch(void* const* d_in, const int* in_sizes, int n_in,
                              void* d_out, int out_size, void* d_ws, size_t ws_size,
                              hipStream_t stream)
{
    const float* x  = (const float*)d_in[0];
    const float* Wq = (const float*)d_in[1];
    const float* bq = (const float*)d_in[2];
    const float* Wk = (const float*)d_in[3];
    const float* bk = (const float*)d_in[4];
    const float* Wv = (const float*)d_in[5];
    const float* bv = (const float*)d_in[6];
    float* out = (float*)d_out;

    const size_t n = (size_t)BB * LL * CC;
    unsigned short* Qb = (unsigned short*)d_ws;
    unsigned short* Kb = Qb + n;
    unsigned short* Vt = Kb + n;

    hipLaunchKernelGGL(k_qkv, dim3(3 * BB * LL / 64), dim3(512), 0, stream,
                       x, Wq, bq, Wk, bk, Wv, bv, Qb, Kb, Vt);
    hipLaunchKernelGGL(k_stats, dim3(BB * (LL / 32)), dim3(256), 0, stream,
                       Qb, Kb, Vt);
    hipLaunchKernelGGL(k_out, dim3(BB * (LL / 32)), dim3(256), 0, stream,
                       x, Qb, Kb, Vt, out);
}

// Round 7
// 88.140 us; speedup vs baseline: 2.3809x; 1.4859x over previous
//
#include <hip/hip_runtime.h>
#include <math.h>

// Attention1D: B=4, L=4096, C=F=64, fp32 in/out.
// scores=(QK^T)/8; softmax over QUERY axis; out = P@V + x = E@(diag(rl)V) + x.
// k_stats folds rl into V^T. All matmuls mfma_f32_32x32x16_bf16 with
// swapped-operand S^T; PV fragments assembled in-register (shfl_xor(32)).
// v7: all in-loop global GATHERS -> coalesced asm GLD4 staging + LDS tiles
// (row stride 136B => 2-way-free bank pattern), T14 issue-early/write-late.

#define BB 4
#define LL 4096
#define CC 64
#define LDW 68   // LDS tile row stride in ushorts (136B)
#define C2 0.18033688011112042f  // 0.125 * log2(e)

typedef __attribute__((ext_vector_type(8)))  short bf16x8;
typedef __attribute__((ext_vector_type(4)))  float f32x4;
typedef __attribute__((ext_vector_type(16))) float f32x16;
typedef __attribute__((ext_vector_type(4)))  unsigned int u32x4;

#define MFMA16(a, b, c) __builtin_amdgcn_mfma_f32_16x16x32_bf16(a, b, c, 0, 0, 0)
#define MFMA32(a, b, c) __builtin_amdgcn_mfma_f32_32x32x16_bf16(a, b, c, 0, 0, 0)
#define EXP2(x) __builtin_amdgcn_exp2f(x)

#define GLD4(dst, voff, base, imm) \
    asm volatile("global_load_dwordx4 %0, %1, %2 offset:%c3" \
                 : "=v"(dst) : "v"(voff), "s"(base), "i"(imm))
#define WAITVM0() asm volatile("s_waitcnt vmcnt(0)" ::: "memory")
#define LGKM0()   asm volatile("s_waitcnt lgkmcnt(0)" ::: "memory")
#define SBAR() __builtin_amdgcn_sched_barrier(0)

static __device__ __forceinline__ bf16x8 asbf(u32x4 v) {
    union { u32x4 a; bf16x8 b; } u; u.a = v; return u.b;
}
static __device__ __forceinline__ unsigned short f2bf(float f) {
    union { float f; unsigned u; } v; v.f = f;
    unsigned r = v.u + 0x7FFFu + ((v.u >> 16) & 1u);
    return (unsigned short)(r >> 16);
}
static __device__ __forceinline__ float bf2f(unsigned short h) {
    union { unsigned u; float f; } v; v.u = ((unsigned)h) << 16; return v.f;
}
static __device__ __forceinline__ bf16x8 pack8(float4 a, float4 b) {
    bf16x8 r;
    r[0] = (short)f2bf(a.x); r[1] = (short)f2bf(a.y);
    r[2] = (short)f2bf(a.z); r[3] = (short)f2bf(a.w);
    r[4] = (short)f2bf(b.x); r[5] = (short)f2bf(b.y);
    r[6] = (short)f2bf(b.z); r[7] = (short)f2bf(b.w);
    return r;
}
static __device__ __forceinline__ unsigned cvtpk(float lo, float hi) {
    unsigned r;
    asm("v_cvt_pk_bf16_f32 %0, %1, %2" : "=v"(r) : "v"(lo), "v"(hi));
    return r;
}
static __device__ __forceinline__ bf16x8 lds_frag(const unsigned short* p) {
    union { uint2 u[2]; bf16x8 b; } t;
    t.u[0] = *(const uint2*)(p);
    t.u[1] = *(const uint2*)(p + 4);
    return t.b;
}
static __device__ __forceinline__ void lds_put(unsigned short* p, u32x4 v) {
    *(uint2*)(p)     = make_uint2(v[0], v[1]);
    *(uint2*)(p + 4) = make_uint2(v[2], v[3]);
}

// ---------------- K1: projections via MFMA -> bf16 Q, K, V^T ----------------
__global__ __launch_bounds__(512) void k_qkv(
    const float* __restrict__ x,
    const float* __restrict__ Wq, const float* __restrict__ bq,
    const float* __restrict__ Wk, const float* __restrict__ bk,
    const float* __restrict__ Wv, const float* __restrict__ bv,
    unsigned short* __restrict__ Qb, unsigned short* __restrict__ Kb,
    unsigned short* __restrict__ Vt)
{
    __shared__ float Wl[64 * 64];             // 16 KB staged weight
    __shared__ unsigned short ldsV[64 * 72];
    const int bid = blockIdx.x;
    const int mat = bid % 3;          // 0:Q 1:K 2:V
    const int r0 = (bid / 3) * 64;
    const int tid = threadIdx.x, w = tid >> 6, lane = tid & 63;
    const int c = lane & 15, g = lane >> 4;
    const int rw = (w >> 1) * 16;
    const int c0 = (w & 1) * 32;

    const float* W  = (mat == 0) ? Wq : (mat == 1) ? Wk : Wv;
    const float* bs = (mat == 0) ? bq : (mat == 1) ? bk : bv;

    {   // coalesced W stage
        const float4* wsrc = (const float4*)W;
        float4* wdst = (float4*)Wl;
        wdst[tid] = wsrc[tid];
        wdst[tid + 512] = wsrc[tid + 512];
    }

    const float* xr = x + (size_t)(r0 + rw + c) * CC;
    const bf16x8 ax0 = pack8(((const float4*)xr)[2 * g], ((const float4*)xr)[2 * g + 1]);
    const bf16x8 ax1 = pack8(((const float4*)xr)[8 + 2 * g], ((const float4*)xr)[8 + 2 * g + 1]);
    __syncthreads();   // Wl ready

    f32x4 acc0 = {0.f, 0.f, 0.f, 0.f}, acc1 = {0.f, 0.f, 0.f, 0.f};
    {
        const int col = c0 + c;
        bf16x8 b0, b1;
        #pragma unroll
        for (int j = 0; j < 8; ++j) {
            b0[j] = (short)f2bf(Wl[(8 * g + j) * 64 + col]);
            b1[j] = (short)f2bf(Wl[(32 + 8 * g + j) * 64 + col]);
        }
        acc0 = MFMA16(ax0, b0, acc0); acc0 = MFMA16(ax1, b1, acc0);
    }
    {
        const int col = c0 + 16 + c;
        bf16x8 b0, b1;
        #pragma unroll
        for (int j = 0; j < 8; ++j) {
            b0[j] = (short)f2bf(Wl[(8 * g + j) * 64 + col]);
            b1[j] = (short)f2bf(Wl[(32 + 8 * g + j) * 64 + col]);
        }
        acc1 = MFMA16(ax0, b0, acc1); acc1 = MFMA16(ax1, b1, acc1);
    }
    const float bias0 = bs[c0 + c], bias1 = bs[c0 + 16 + c];

    if (mat < 2) {
        unsigned short* dst = (mat == 0) ? Qb : Kb;
        #pragma unroll
        for (int r = 0; r < 4; ++r) {
            const size_t row = (size_t)(r0 + rw + 4 * g + r) * CC;
            dst[row + c0 + c]      = f2bf(acc0[r] + bias0);
            dst[row + c0 + 16 + c] = f2bf(acc1[r] + bias1);
        }
    } else {
        #pragma unroll
        for (int r = 0; r < 4; ++r) {
            const int rowin = rw + 4 * g + r;
            ldsV[(c0 + c) * 72 + rowin]      = f2bf(acc0[r] + bias0);
            ldsV[(c0 + 16 + c) * 72 + rowin] = f2bf(acc1[r] + bias1);
        }
        __syncthreads();
        const int b = r0 >> 12, rin = r0 & 4095;
        const int f = tid >> 3, jj = tid & 7;
        *(uint4*)(Vt + ((size_t)(b * 64 + f)) * LL + rin + jj * 8) =
            *(const uint4*)(ldsV + f * 72 + jj * 8);
    }
}

// ---------------- K2: column sums -> rescale V^T in place ----------------
// grid = B*(L/32) x 256 (4 waves, wave-private q-quarters, LDS-tiled Q).
__global__ __launch_bounds__(256, 2) void k_stats(
    const unsigned short* __restrict__ Qb, const unsigned short* __restrict__ Kb,
    unsigned short* __restrict__ Vt)
{
    const int nb = ((blockIdx.x & 7) << 6) | (blockIdx.x >> 3);  // XCD swizzle (512 grid)
    const int b = nb >> 7, kt = nb & 127;
    const int kbase = kt * 32;
    const int tid = threadIdx.x, w = tid >> 6, lane = tid & 63;
    const int l31 = lane & 31, hi = lane >> 5;

    __shared__ unsigned short qtile[4][2][64 * LDW];  // 68 KB
    __shared__ float pl[4][32];
    __shared__ float rls[32];

    // loop-invariant A-frags: K rows (one-time gather)
    const unsigned short* kr = Kb + ((size_t)b * LL + kbase + l31) * CC + 8 * hi;
    const bf16x8 ak0 = *(const bf16x8*)(kr);
    const bf16x8 ak1 = *(const bf16x8*)(kr + 16);
    const bf16x8 ak2 = *(const bf16x8*)(kr + 32);
    const bf16x8 ak3 = *(const bf16x8*)(kr + 48);

    const unsigned short* const sQ = Qb + (size_t)b * LL * CC;
    const int rlo = lane >> 3, jj8 = (lane & 7) * 8;
    const unsigned qvbase = (unsigned)(((w * 1024 + rlo) * CC + jj8) * 2);
    const int woff = rlo * LDW + (lane & 7) * 8;

    u32x4 S0, S1, S2, S3, S4, S5, S6, S7;
    #define QSTG(s_) do { \
        unsigned vo = qvbase + (unsigned)(s_) * 8192u; \
        GLD4(S0, vo, sQ, 0); GLD4(S1, vo, sQ, 1024); \
        GLD4(S2, vo, sQ, 2048); GLD4(S3, vo, sQ, 3072); \
        vo += 4096u; \
        GLD4(S4, vo, sQ, 0); GLD4(S5, vo, sQ, 1024); \
        GLD4(S6, vo, sQ, 2048); GLD4(S7, vo, sQ, 3072); \
    } while (0)
    #define QWR(dst) do { \
        unsigned short* _p = (dst) + woff; \
        lds_put(_p, S0);            lds_put(_p + 8 * LDW, S1); \
        lds_put(_p + 16 * LDW, S2); lds_put(_p + 24 * LDW, S3); \
        lds_put(_p + 32 * LDW, S4); lds_put(_p + 40 * LDW, S5); \
        lds_put(_p + 48 * LDW, S6); lds_put(_p + 56 * LDW, S7); \
    } while (0)

    QSTG(0); WAITVM0(); SBAR();
    QWR(&qtile[w][0][0]);

    f32x16 lacc = {};
    for (int s = 0; s < 16; ++s) {
        LGKM0(); SBAR();                 // tile s visible; stage regs free
        if (s < 15) QSTG(s + 1);
        const unsigned short* Qt = &qtile[w][s & 1][0];
        #pragma unroll
        for (int qs = 0; qs < 2; ++qs) {
            const int rq = (qs * 32 + l31) * LDW;
            const bf16x8 b0 = lds_frag(Qt + rq + (0 + hi) * 8);
            const bf16x8 b1 = lds_frag(Qt + rq + (2 + hi) * 8);
            const bf16x8 b2 = lds_frag(Qt + rq + (4 + hi) * 8);
            const bf16x8 b3 = lds_frag(Qt + rq + (6 + hi) * 8);
            f32x16 T = {};
            T = MFMA32(ak0, b0, T); T = MFMA32(ak1, b1, T);
            T = MFMA32(ak2, b2, T); T = MFMA32(ak3, b3, T);
            #pragma unroll
            for (int r = 0; r < 16; ++r) lacc[r] += EXP2(T[r] * C2);
        }
        WAITVM0(); SBAR();               // stage loads (s+1) arrived
        if (s < 15) QWR(&qtile[w][(s + 1) & 1][0]);
    }
    #undef QSTG
    #undef QWR

    // reduce over q (32 lanes of each half)
    #pragma unroll
    for (int r = 0; r < 16; ++r) {
        float v = lacc[r];
        v += __shfl_xor(v, 1);  v += __shfl_xor(v, 2);
        v += __shfl_xor(v, 4);  v += __shfl_xor(v, 8);
        v += __shfl_xor(v, 16);
        lacc[r] = v;
    }
    if (l31 == 0) {
        #pragma unroll
        for (int r = 0; r < 16; ++r)
            pl[w][(r & 3) + 8 * (r >> 2) + 4 * hi] = lacc[r];
    }
    __syncthreads();
    if (tid < 32) {
        const float L = (pl[0][tid] + pl[1][tid]) + (pl[2][tid] + pl[3][tid]);
        rls[tid] = 1.0f / L;
    }
    __syncthreads();

    // rescale V^T in place for k-columns [kbase, kbase+32)
    {
        const int f = tid >> 2, jj = tid & 3;
        unsigned short* vp = Vt + ((size_t)(b * 64 + f)) * LL + kbase + jj * 8;
        ushort4 v0 = ((const ushort4*)vp)[0], v1 = ((const ushort4*)vp)[1];
        v0.x = f2bf(bf2f(v0.x) * rls[jj * 8 + 0]);
        v0.y = f2bf(bf2f(v0.y) * rls[jj * 8 + 1]);
        v0.z = f2bf(bf2f(v0.z) * rls[jj * 8 + 2]);
        v0.w = f2bf(bf2f(v0.w) * rls[jj * 8 + 3]);
        v1.x = f2bf(bf2f(v1.x) * rls[jj * 8 + 4]);
        v1.y = f2bf(bf2f(v1.y) * rls[jj * 8 + 5]);
        v1.z = f2bf(bf2f(v1.z) * rls[jj * 8 + 6]);
        v1.w = f2bf(bf2f(v1.w) * rls[jj * 8 + 7]);
        ((ushort4*)vp)[0] = v0; ((ushort4*)vp)[1] = v1;
    }
}

// ---------------- K3: out = E @ V' + x ----------------
// grid = B*(L/64) = 256 blocks x 512 thr (8 waves = 2 qsub x 4 ksp).
// Per 64-k step: coalesced-stage K,V tiles (dbuf LDS) -> LDS frags ->
// S^T MFMA -> exp/cvt_pk/shfl_xor(32) E-frags -> PV MFMA.
__global__ __launch_bounds__(512, 2) void k_out(
    const float* __restrict__ x,
    const unsigned short* __restrict__ Qb, const unsigned short* __restrict__ Kb,
    const unsigned short* __restrict__ Vt,
    float* __restrict__ out)
{
    const int nb = ((blockIdx.x & 7) << 5) | (blockIdx.x >> 3);  // XCD swizzle (256 grid)
    const int b = nb >> 6, qt = nb & 63;
    const int q0 = qt * 64;
    const int tid = threadIdx.x, w = tid >> 6, lane = tid & 63;
    const int l31 = lane & 31, hi = lane >> 5;
    const int qsub = w & 1, ksp = w >> 1;

    __shared__ unsigned short ktile[4][2][64 * LDW];  // 68 KB
    __shared__ unsigned short vtile[4][2][64 * LDW];  // 68 KB

    // loop-invariant Q B-frags (one-time gather)
    const unsigned short* qr = Qb + ((size_t)b * LL + q0 + qsub * 32 + l31) * CC + 8 * hi;
    const bf16x8 qb0 = *(const bf16x8*)(qr);
    const bf16x8 qb1 = *(const bf16x8*)(qr + 16);
    const bf16x8 qb2 = *(const bf16x8*)(qr + 32);
    const bf16x8 qb3 = *(const bf16x8*)(qr + 48);

    const unsigned short* const sK = Kb + (size_t)b * LL * CC;
    const unsigned short* const sV = Vt + (size_t)b * 64 * LL;
    const int rlo = lane >> 3, jj8 = (lane & 7) * 8;
    const unsigned kvbase = (unsigned)(((ksp * 1024 + rlo) * CC + jj8) * 2);
    const unsigned vvbase = (unsigned)((((unsigned)rlo * LL) + ksp * 1024 + jj8) * 2);
    const int woff = rlo * LDW + (lane & 7) * 8;

    u32x4 S0, S1, S2, S3, S4, S5, S6, S7;
    #define KSTG(s_) do { \
        unsigned vo = kvbase + (unsigned)(s_) * 8192u; \
        GLD4(S0, vo, sK, 0); GLD4(S1, vo, sK, 1024); \
        GLD4(S2, vo, sK, 2048); GLD4(S3, vo, sK, 3072); \
        vo += 4096u; \
        GLD4(S4, vo, sK, 0); GLD4(S5, vo, sK, 1024); \
        GLD4(S6, vo, sK, 2048); GLD4(S7, vo, sK, 3072); \
    } while (0)
    #define VSTG(s_) do { \
        unsigned vo = vvbase + (unsigned)(s_) * 128u; \
        GLD4(S0, vo, sV, 0); vo += 65536u; GLD4(S1, vo, sV, 0); vo += 65536u; \
        GLD4(S2, vo, sV, 0); vo += 65536u; GLD4(S3, vo, sV, 0); vo += 65536u; \
        GLD4(S4, vo, sV, 0); vo += 65536u; GLD4(S5, vo, sV, 0); vo += 65536u; \
        GLD4(S6, vo, sV, 0); vo += 65536u; GLD4(S7, vo, sV, 0); \
    } while (0)
    #define SWRO(dst) do { \
        unsigned short* _p = (dst) + woff; \
        lds_put(_p, S0);            lds_put(_p + 8 * LDW, S1); \
        lds_put(_p + 16 * LDW, S2); lds_put(_p + 24 * LDW, S3); \
        lds_put(_p + 32 * LDW, S4); lds_put(_p + 40 * LDW, S5); \
        lds_put(_p + 48 * LDW, S6); lds_put(_p + 56 * LDW, S7); \
    } while (0)

    // prologue: tile 0
    if (qsub == 0) KSTG(0); else VSTG(0);
    WAITVM0(); SBAR();
    if (qsub == 0) SWRO(&ktile[ksp][0][0]); else SWRO(&vtile[ksp][0][0]);
    __syncthreads();

    f32x16 oacc0 = {}, oacc1 = {};

    for (int s = 0; s < 16; ++s) {
        const int buf = s & 1;
        if (s < 15) { if (qsub == 0) KSTG(s + 1); else VSTG(s + 1); }
        const unsigned short* Kt = &ktile[ksp][buf][0];
        const unsigned short* Vl = &vtile[ksp][buf][0];
        #pragma unroll
        for (int ks = 0; ks < 2; ++ks) {
            const int rowk = (ks * 32 + l31) * LDW;
            const bf16x8 ak0 = lds_frag(Kt + rowk + (0 + hi) * 8);
            const bf16x8 ak1 = lds_frag(Kt + rowk + (2 + hi) * 8);
            const bf16x8 ak2 = lds_frag(Kt + rowk + (4 + hi) * 8);
            const bf16x8 ak3 = lds_frag(Kt + rowk + (6 + hi) * 8);
            f32x16 T = {};
            T = MFMA32(ak0, qb0, T); T = MFMA32(ak1, qb1, T);
            T = MFMA32(ak2, qb2, T); T = MFMA32(ak3, qb3, T);
            const unsigned u0 = cvtpk(EXP2(T[0] * C2),  EXP2(T[1] * C2));
            const unsigned u1 = cvtpk(EXP2(T[2] * C2),  EXP2(T[3] * C2));
            const unsigned u2 = cvtpk(EXP2(T[4] * C2),  EXP2(T[5] * C2));
            const unsigned u3 = cvtpk(EXP2(T[6] * C2),  EXP2(T[7] * C2));
            const unsigned u4 = cvtpk(EXP2(T[8] * C2),  EXP2(T[9] * C2));
            const unsigned u5 = cvtpk(EXP2(T[10] * C2), EXP2(T[11] * C2));
            const unsigned u6 = cvtpk(EXP2(T[12] * C2), EXP2(T[13] * C2));
            const unsigned u7 = cvtpk(EXP2(T[14] * C2), EXP2(T[15] * C2));
            const unsigned t0 = (unsigned)__shfl_xor((int)u0, 32);
            const unsigned t1 = (unsigned)__shfl_xor((int)u1, 32);
            const unsigned t2 = (unsigned)__shfl_xor((int)u2, 32);
            const unsigned t3 = (unsigned)__shfl_xor((int)u3, 32);
            const unsigned t4 = (unsigned)__shfl_xor((int)u4, 32);
            const unsigned t5 = (unsigned)__shfl_xor((int)u5, 32);
            const unsigned t6 = (unsigned)__shfl_xor((int)u6, 32);
            const unsigned t7 = (unsigned)__shfl_xor((int)u7, 32);
            u32x4 f1, f2;
            f1[0] = hi ? t2 : u0;  f1[1] = hi ? t3 : u1;
            f1[2] = hi ? u2 : t0;  f1[3] = hi ? u3 : t1;
            f2[0] = hi ? t6 : u4;  f2[1] = hi ? t7 : u5;
            f2[2] = hi ? u6 : t4;  f2[3] = hi ? u7 : t5;
            const int rv = l31 * LDW;
            const bf16x8 v00 = lds_frag(Vl + rv + (ks * 4 + hi) * 8);
            const bf16x8 v01 = lds_frag(Vl + rv + (ks * 4 + 2 + hi) * 8);
            const bf16x8 v10 = lds_frag(Vl + 32 * LDW + rv + (ks * 4 + hi) * 8);
            const bf16x8 v11 = lds_frag(Vl + 32 * LDW + rv + (ks * 4 + 2 + hi) * 8);
            oacc0 = MFMA32(v00, asbf(f1), oacc0);
            oacc0 = MFMA32(v01, asbf(f2), oacc0);
            oacc1 = MFMA32(v10, asbf(f1), oacc1);
            oacc1 = MFMA32(v11, asbf(f2), oacc1);
        }
        WAITVM0(); SBAR();    // stage loads (s+1) arrived
        if (s < 15) { if (qsub == 0) SWRO(&ktile[ksp][buf ^ 1][0]); else SWRO(&vtile[ksp][buf ^ 1][0]); }
        __syncthreads();
    }
    #undef KSTG
    #undef VSTG
    #undef SWRO

    // combine 8 waves' partial O^T tiles; ocomb aliases ktile (done with it)
    float* ocomb = (float*)&ktile[0][0][0];   // [64 q][68]
    for (int i = tid; i < 64 * LDW; i += 512) ocomb[i] = 0.f;
    __syncthreads();
    #pragma unroll
    for (int r = 0; r < 16; ++r) {
        const int fr = (r & 3) + 8 * (r >> 2) + 4 * hi;
        const int qq = qsub * 32 + l31;
        atomicAdd(&ocomb[qq * LDW + fr],      oacc0[r]);
        atomicAdd(&ocomb[qq * LDW + 32 + fr], oacc1[r]);
    }
    __syncthreads();
    {
        const int q = tid >> 3, f8 = (tid & 7) * 8;
        const size_t row = (size_t)b * LL + q0 + q;
        const float4 xv0 = ((const float4*)(x + row * CC))[f8 >> 2];
        const float4 xv1 = ((const float4*)(x + row * CC))[(f8 >> 2) + 1];
        const float4 ov0 = *(const float4*)(&ocomb[q * LDW + f8]);
        const float4 ov1 = *(const float4*)(&ocomb[q * LDW + f8 + 4]);
        ((float4*)(out + row * CC))[f8 >> 2] =
            make_float4(xv0.x + ov0.x, xv0.y + ov0.y, xv0.z + ov0.z, xv0.w + ov0.w);
        ((float4*)(out + row * CC))[(f8 >> 2) + 1] =
            make_float4(xv1.x + ov1.x, xv1.y + ov1.y, xv1.z + ov1.z, xv1.w + ov1.w);
    }
}

extern "C" void kernel_launch(void* const* d_in, const int* in_sizes, int n_in,
                              void* d_out, int out_size, void* d_ws, size_t ws_size,
                              hipStream_t stream)
{
    const float* x  = (const float*)d_in[0];
    const float* Wq = (const float*)d_in[1];
    const float* bq = (const float*)d_in[2];
    const float* Wk = (const float*)d_in[3];
    const float* bk = (const float*)d_in[4];
    const float* Wv = (const float*)d_in[5];
    const float* bv = (const float*)d_in[6];
    float* out = (float*)d_out;

    const size_t n = (size_t)BB * LL * CC;
    unsigned short* Qb = (unsigned short*)d_ws;
    unsigned short* Kb = Qb + n;
    unsigned short* Vt = Kb + n;

    hipLaunchKernelGGL(k_qkv, dim3(3 * BB * LL / 64), dim3(512), 0, stream,
                       x, Wq, bq, Wk, bk, Wv, bv, Qb, Kb, Vt);
    hipLaunchKernelGGL(k_stats, dim3(BB * (LL / 32)), dim3(256), 0, stream,
                       Qb, Kb, Vt);
    hipLaunchKernelGGL(k_out, dim3(BB * (LL / 64)), dim3(512), 0, stream,
                       x, Qb, Kb, Vt, out);
}